// Round 1
// baseline (13761.768 us; speedup 1.0000x reference)
//
#include <hip/hip_runtime.h>

// ---------------------------------------------------------------------------
// MagNet link prediction forward pass, f32 throughout.
//
// Pipeline per layer (GEMM-first formulation; prop commutes with right-mult):
//   G1r=xr@W1, G1i=xi@W1, G2r=xr@W2, G2i=xi@W2, hr=(xr-xi)@(W0-W2)+b,
//   hi=(xr+xi)@(W0-W2)+b
//   pass A (1M directed edges): hr[d] += cr*G1r[s]-ci*G1i[s]; hi[d] += ci*G1r[s]+cr*G1i[s]
//                               U0[d]+=cr*G2r[s]; U1[d]+=ci*G2i[s]; U2[d]+=ci*G2r[s]; U3[d]+=cr*G2i[s]
//   pass B: hr[d] += 2(cr*U0[s]-ci*U1[s]); hi[d] += 2(ci*U2[s]+cr*U3[s])
//   complex relu (mask = hr>=0)
// Reverse edges share forward coefficients with ni -> -ni, so each thread
// group processes both directions of one undirected edge.
// ---------------------------------------------------------------------------

__device__ __forceinline__ void at4(float* __restrict__ p, float4 v) {
  unsafeAtomicAdd(p + 0, v.x);
  unsafeAtomicAdd(p + 1, v.y);
  unsafeAtomicAdd(p + 2, v.z);
  unsafeAtomicAdd(p + 3, v.w);
}
__device__ __forceinline__ float4 cmul4(float s, float4 a) {
  return make_float4(s * a.x, s * a.y, s * a.z, s * a.w);
}
__device__ __forceinline__ float4 fma4(float s, float4 a, float t, float4 b) {
  return make_float4(s * a.x + t * b.x, s * a.y + t * b.y,
                     s * a.z + t * b.z, s * a.w + t * b.w);
}
__device__ __forceinline__ float4 ld4(const float* __restrict__ p) {
  return *reinterpret_cast<const float4*>(p);
}

// ---- degree: deg[n] = sum of 0.5*w over incident edges (both endpoints) ----
__global__ void k_deg(const int* __restrict__ u, const int* __restrict__ v,
                      const float* __restrict__ w, float* __restrict__ deg, int E) {
  int e = blockIdx.x * 256 + threadIdx.x;
  if (e >= E) return;
  float hw = 0.5f * w[e];
  unsafeAtomicAdd(&deg[u[e]], hw);
  unsafeAtomicAdd(&deg[v[e]], hw);
}

// ---- per-edge coefficients (forward direction; reverse flips sign of ni) ---
__global__ void k_coeff(const int* __restrict__ u, const int* __restrict__ v,
                        const float* __restrict__ w, const float* __restrict__ deg,
                        float* __restrict__ nr, float* __restrict__ ni, int E) {
  int e = blockIdx.x * 256 + threadIdx.x;
  if (e >= E) return;
  float we = w[e];
  float da = deg[u[e]], db = deg[v[e]];
  float ia = da > 0.f ? rsqrtf(da) : 0.f;
  float ib = db > 0.f ? rsqrtf(db) : 0.f;
  float norm = ia * (0.5f * we) * ib;
  float th = 1.57079632679489662f * we;  // 2*pi*q*w, q = 0.25
  float s = sinf(th), c = cosf(th);
  nr[e] = -norm * c;
  ni[e] = -norm * s;
}

// ---- Wm = W[0] - W[2] -------------------------------------------------------
__global__ void k_wsub(const float* __restrict__ W, float* __restrict__ out, int n) {
  int i = blockIdx.x * 256 + threadIdx.x;
  if (i < n) out[i] = W[i] - W[2 * n + i];
}

// ---- tiled f32 GEMM: C(M x 64) = A(M x K) @ W(K x 64) ----------------------
template <int K>
__global__ __launch_bounds__(256) void k_gemm(const float* __restrict__ A,
                                              const float* __restrict__ W,
                                              float* __restrict__ C, int M) {
  __shared__ float As[64][68];
  __shared__ float Ws[64][64];
  const int t = threadIdx.x;
  const int r0 = blockIdx.x * 64;
  const int tc = t & 15, tr = t >> 4;
  float acc[4][4] = {};
  for (int k0 = 0; k0 < K; k0 += 64) {
    for (int li = t; li < 64 * 16; li += 256) {
      int row = li >> 4, c4 = li & 15;
      int gr = r0 + row;
      float4 a4 = (gr < M) ? ld4(&A[(size_t)gr * K + k0 + c4 * 4])
                           : make_float4(0.f, 0.f, 0.f, 0.f);
      *reinterpret_cast<float4*>(&As[row][c4 * 4]) = a4;
    }
    for (int li = t; li < 64 * 16; li += 256) {
      int row = li >> 4, c4 = li & 15;
      *reinterpret_cast<float4*>(&Ws[row][c4 * 4]) =
          ld4(&W[(size_t)(k0 + row) * 64 + c4 * 4]);
    }
    __syncthreads();
    for (int k = 0; k < 64; ++k) {
      float4 b4 = *reinterpret_cast<const float4*>(&Ws[k][tc * 4]);
      float a0 = As[tr * 4 + 0][k], a1 = As[tr * 4 + 1][k];
      float a2 = As[tr * 4 + 2][k], a3 = As[tr * 4 + 3][k];
      acc[0][0] += a0 * b4.x; acc[0][1] += a0 * b4.y; acc[0][2] += a0 * b4.z; acc[0][3] += a0 * b4.w;
      acc[1][0] += a1 * b4.x; acc[1][1] += a1 * b4.y; acc[1][2] += a1 * b4.z; acc[1][3] += a1 * b4.w;
      acc[2][0] += a2 * b4.x; acc[2][1] += a2 * b4.y; acc[2][2] += a2 * b4.z; acc[2][3] += a2 * b4.w;
      acc[3][0] += a3 * b4.x; acc[3][1] += a3 * b4.y; acc[3][2] += a3 * b4.z; acc[3][3] += a3 * b4.w;
    }
    __syncthreads();
  }
#pragma unroll
  for (int i = 0; i < 4; ++i) {
    int gr = r0 + tr * 4 + i;
    if (gr < M)
      *reinterpret_cast<float4*>(&C[(size_t)gr * 64 + tc * 4]) =
          make_float4(acc[i][0], acc[i][1], acc[i][2], acc[i][3]);
  }
}

// ---- hr = Hr0 - Hi0 + b ; hi = Hr0 + Hi0 + b (in place on Hr0/Hi0) ---------
__global__ void k_hb(float* __restrict__ Hr, float* __restrict__ Hi,
                     const float* __restrict__ b, int n) {
  int i = blockIdx.x * 256 + threadIdx.x;
  if (i >= n) return;
  float p = Hr[i], q = Hi[i], bb = b[i & 63];
  Hr[i] = p - q + bb;
  Hi[i] = p + q + bb;
}

// ---- edge pass A: T1 contributions into hr/hi, and U0..U3 ------------------
__global__ __launch_bounds__(256) void k_passA(
    const int* __restrict__ us, const int* __restrict__ vs,
    const float* __restrict__ nr, const float* __restrict__ ni,
    const float* __restrict__ G1r, const float* __restrict__ G1i,
    const float* __restrict__ G2r, const float* __restrict__ G2i,
    float* __restrict__ hr, float* __restrict__ hi,
    float* __restrict__ U0, float* __restrict__ U1,
    float* __restrict__ U2, float* __restrict__ U3, int E) {
  int t = blockIdx.x * 256 + threadIdx.x;
  int j = t >> 4;
  if (j >= E) return;
  int f = (t & 15) * 4;
  int a = us[j], b = vs[j];
  float cr = nr[j], ci = ni[j];
  size_t oa = (size_t)a * 64 + f, ob = (size_t)b * 64 + f;
  float4 a1r = ld4(G1r + oa), a1i = ld4(G1i + oa);
  float4 a2r = ld4(G2r + oa), a2i = ld4(G2i + oa);
  float4 b1r = ld4(G1r + ob), b1i = ld4(G1i + ob);
  float4 b2r = ld4(G2r + ob), b2i = ld4(G2i + ob);
  // forward edge: src=a -> dst=b, coeff (cr, ci)
  at4(hr + ob, fma4(cr, a1r, -ci, a1i));
  at4(hi + ob, fma4(ci, a1r, cr, a1i));
  at4(U0 + ob, cmul4(cr, a2r));
  at4(U1 + ob, cmul4(ci, a2i));
  at4(U2 + ob, cmul4(ci, a2r));
  at4(U3 + ob, cmul4(cr, a2i));
  // reverse edge: src=b -> dst=a, coeff (cr, -ci)
  at4(hr + oa, fma4(cr, b1r, ci, b1i));
  at4(hi + oa, fma4(-ci, b1r, cr, b1i));
  at4(U0 + oa, cmul4(cr, b2r));
  at4(U1 + oa, cmul4(-ci, b2i));
  at4(U2 + oa, cmul4(-ci, b2r));
  at4(U3 + oa, cmul4(cr, b2i));
}

// ---- edge pass B: T2 contributions (x2) into hr/hi --------------------------
__global__ __launch_bounds__(256) void k_passB(
    const int* __restrict__ us, const int* __restrict__ vs,
    const float* __restrict__ nr, const float* __restrict__ ni,
    const float* __restrict__ U0, const float* __restrict__ U1,
    const float* __restrict__ U2, const float* __restrict__ U3,
    float* __restrict__ hr, float* __restrict__ hi, int E) {
  int t = blockIdx.x * 256 + threadIdx.x;
  int j = t >> 4;
  if (j >= E) return;
  int f = (t & 15) * 4;
  int a = us[j], b = vs[j];
  float cr2 = 2.f * nr[j], ci2 = 2.f * ni[j];
  size_t oa = (size_t)a * 64 + f, ob = (size_t)b * 64 + f;
  float4 u0a = ld4(U0 + oa), u1a = ld4(U1 + oa), u2a = ld4(U2 + oa), u3a = ld4(U3 + oa);
  float4 u0b = ld4(U0 + ob), u1b = ld4(U1 + ob), u2b = ld4(U2 + ob), u3b = ld4(U3 + ob);
  // forward: dst=b
  at4(hr + ob, fma4(cr2, u0a, -ci2, u1a));
  at4(hi + ob, fma4(ci2, u2a, cr2, u3a));
  // reverse: dst=a, coeff (cr, -ci)
  at4(hr + oa, fma4(cr2, u0b, ci2, u1b));
  at4(hi + oa, fma4(-ci2, u2b, cr2, u3b));
}

// ---- complex relu (mask from real part), in place ---------------------------
__global__ void k_crelu(float* __restrict__ xr, float* __restrict__ xi, int n) {
  int i = blockIdx.x * 256 + threadIdx.x;
  if (i >= n) return;
  if (xr[i] < 0.f) { xr[i] = 0.f; xi[i] = 0.f; }
}

// ---- query gather + linear + log_softmax ------------------------------------
__global__ __launch_bounds__(256) void k_query(
    const int* __restrict__ qe, const float* __restrict__ xr,
    const float* __restrict__ xi, const float* __restrict__ Wlin,
    const float* __restrict__ blin, float* __restrict__ out, int Q) {
  int q = blockIdx.x * 4 + (threadIdx.x >> 6);
  if (q >= Q) return;
  int lane = threadIdx.x & 63;
  int q0 = qe[2 * q], q1 = qe[2 * q + 1];
  float x0 = xr[(size_t)q0 * 64 + lane];
  float x1 = xr[(size_t)q1 * 64 + lane];
  float x2 = xi[(size_t)q0 * 64 + lane];
  float x3 = xi[(size_t)q1 * 64 + lane];
  float l0 = x0 * Wlin[lane] + x1 * Wlin[64 + lane] + x2 * Wlin[128 + lane] + x3 * Wlin[192 + lane];
  float l1 = x0 * Wlin[256 + lane] + x1 * Wlin[320 + lane] + x2 * Wlin[384 + lane] + x3 * Wlin[448 + lane];
#pragma unroll
  for (int o = 32; o > 0; o >>= 1) {
    l0 += __shfl_xor(l0, o);
    l1 += __shfl_xor(l1, o);
  }
  if (lane == 0) {
    l0 += blin[0];
    l1 += blin[1];
    float m = fmaxf(l0, l1);
    float lse = m + logf(expf(l0 - m) + expf(l1 - m));
    out[2 * q + 0] = l0 - lse;
    out[2 * q + 1] = l1 - lse;
  }
}

extern "C" void kernel_launch(void* const* d_in, const int* in_sizes, int n_in,
                              void* d_out, int out_size, void* d_ws, size_t ws_size,
                              hipStream_t stream) {
  const float* real = (const float*)d_in[0];
  const float* imag = (const float*)d_in[1];
  const int* ei     = (const int*)d_in[2];
  const int* qe     = (const int*)d_in[3];
  const float* ew   = (const float*)d_in[4];
  const float* W1   = (const float*)d_in[5];
  const float* b1   = (const float*)d_in[6];
  const float* W2   = (const float*)d_in[7];
  const float* b2   = (const float*)d_in[8];
  const float* Wlin = (const float*)d_in[9];
  const float* blin = (const float*)d_in[10];

  const int N = in_sizes[0] / 128;
  const int E = in_sizes[4];
  const int Q = in_sizes[3] / 2;
  const int* u = ei;
  const int* v = ei + E;

  float* ws = (float*)d_ws;
  size_t off = 0;
  auto alloc = [&](size_t n) { float* p = ws + off; off += n; return p; };
  const size_t N64 = (size_t)N * 64;
  float* S[12];
  for (int i = 0; i < 12; ++i) S[i] = alloc(N64);  // contiguous: S6..S9 one memset
  float* deg = alloc(N);
  float* nr  = alloc(E);
  float* ni  = alloc(E);
  float* Wm1 = alloc(128 * 64);
  float* Wm2 = alloc(64 * 64);
  (void)ws_size; (void)n_in; (void)out_size;

  const int eb   = (E + 255) / 256;
  const int mb   = (N + 63) / 64;
  const int nb64 = (int)((N64 + 255) / 256);
  const int ebA  = (int)(((size_t)E * 16 + 255) / 256);

  // --- graph coefficients ---
  hipMemsetAsync(deg, 0, (size_t)N * sizeof(float), stream);
  k_deg<<<eb, 256, 0, stream>>>(u, v, ew, deg, E);
  k_coeff<<<eb, 256, 0, stream>>>(u, v, ew, deg, nr, ni, E);
  k_wsub<<<(128 * 64 + 255) / 256, 256, 0, stream>>>(W1, Wm1, 128 * 64);
  k_wsub<<<(64 * 64 + 255) / 256, 256, 0, stream>>>(W2, Wm2, 64 * 64);

  // --- layer 1 (F=128) ---
  k_gemm<128><<<mb, 256, 0, stream>>>(real, W1 + 128 * 64, S[0], N);      // G1r
  k_gemm<128><<<mb, 256, 0, stream>>>(imag, W1 + 128 * 64, S[1], N);      // G1i
  k_gemm<128><<<mb, 256, 0, stream>>>(real, W1 + 2 * 128 * 64, S[2], N);  // G2r
  k_gemm<128><<<mb, 256, 0, stream>>>(imag, W1 + 2 * 128 * 64, S[3], N);  // G2i
  k_gemm<128><<<mb, 256, 0, stream>>>(real, Wm1, S[4], N);                // Hr0
  k_gemm<128><<<mb, 256, 0, stream>>>(imag, Wm1, S[5], N);                // Hi0
  k_hb<<<nb64, 256, 0, stream>>>(S[4], S[5], b1, (int)N64);
  hipMemsetAsync(S[6], 0, 4 * N64 * sizeof(float), stream);
  k_passA<<<ebA, 256, 0, stream>>>(u, v, nr, ni, S[0], S[1], S[2], S[3],
                                   S[4], S[5], S[6], S[7], S[8], S[9], E);
  k_passB<<<ebA, 256, 0, stream>>>(u, v, nr, ni, S[6], S[7], S[8], S[9],
                                   S[4], S[5], E);
  k_crelu<<<nb64, 256, 0, stream>>>(S[4], S[5], (int)N64);

  // --- layer 2 (F=64) ---
  k_gemm<64><<<mb, 256, 0, stream>>>(S[4], W2 + 64 * 64, S[0], N);
  k_gemm<64><<<mb, 256, 0, stream>>>(S[5], W2 + 64 * 64, S[1], N);
  k_gemm<64><<<mb, 256, 0, stream>>>(S[4], W2 + 2 * 64 * 64, S[2], N);
  k_gemm<64><<<mb, 256, 0, stream>>>(S[5], W2 + 2 * 64 * 64, S[3], N);
  k_gemm<64><<<mb, 256, 0, stream>>>(S[4], Wm2, S[10], N);
  k_gemm<64><<<mb, 256, 0, stream>>>(S[5], Wm2, S[11], N);
  k_hb<<<nb64, 256, 0, stream>>>(S[10], S[11], b2, (int)N64);
  hipMemsetAsync(S[6], 0, 4 * N64 * sizeof(float), stream);
  k_passA<<<ebA, 256, 0, stream>>>(u, v, nr, ni, S[0], S[1], S[2], S[3],
                                   S[10], S[11], S[6], S[7], S[8], S[9], E);
  k_passB<<<ebA, 256, 0, stream>>>(u, v, nr, ni, S[6], S[7], S[8], S[9],
                                   S[10], S[11], E);
  k_crelu<<<nb64, 256, 0, stream>>>(S[10], S[11], (int)N64);

  // --- queries ---
  k_query<<<(Q + 3) / 4, 256, 0, stream>>>(qe, S[10], S[11], Wlin, blin,
                                           (float*)d_out, Q);
}

// Round 2
// 903.355 us; speedup vs baseline: 15.2341x; 15.2341x over previous
//
#include <hip/hip_runtime.h>

// ---------------------------------------------------------------------------
// MagNet link prediction forward, f32. Gather (CSR) formulation — no float
// atomics. Per call:
//   1) deg + in-degree count -> exclusive scan -> scatter (src,cr,ci) records
//      into per-destination buckets (16B per directed edge).
//   2) per layer: packed GEMM  C[N x 192] = x @ [W1 | W2 | W0-W2], for real
//      and imag; gatherA (one wave per node) accumulates T1 into hr/hi and
//      builds U0..U3; gatherB accumulates T2 (2*prop(U)) and applies complex
//      ReLU in the same store.
//   3) query gather + 2-class linear + log_softmax.
// Reverse edges reuse forward coefficients with ni -> -ni.
// ---------------------------------------------------------------------------

__device__ __forceinline__ float4 ld4(const float* __restrict__ p) {
  return *reinterpret_cast<const float4*>(p);
}

// ---- degree (0.5*w per endpoint) + incident-edge count ----------------------
__global__ void k_deg_count(const int* __restrict__ u, const int* __restrict__ v,
                            const float* __restrict__ w, float* __restrict__ deg,
                            int* __restrict__ cnt, int E) {
  int e = blockIdx.x * 256 + threadIdx.x;
  if (e >= E) return;
  float hw = 0.5f * w[e];
  int a = u[e], b = v[e];
  unsafeAtomicAdd(&deg[a], hw);
  unsafeAtomicAdd(&deg[b], hw);
  atomicAdd(&cnt[a], 1);
  atomicAdd(&cnt[b], 1);
}

// ---- exclusive scan of cnt[N] -> rp, 1024 elems per block -------------------
__global__ __launch_bounds__(256) void k_scan1(const int* __restrict__ cnt,
                                               int* __restrict__ rp,
                                               int* __restrict__ bsum, int N) {
  __shared__ int sh[256];
  int t = threadIdx.x;
  int base = blockIdx.x * 1024 + t * 4;
  int c0 = (base + 0 < N) ? cnt[base + 0] : 0;
  int c1 = (base + 1 < N) ? cnt[base + 1] : 0;
  int c2 = (base + 2 < N) ? cnt[base + 2] : 0;
  int c3 = (base + 3 < N) ? cnt[base + 3] : 0;
  int s = c0 + c1 + c2 + c3;
  sh[t] = s;
  __syncthreads();
  for (int o = 1; o < 256; o <<= 1) {
    int y = (t >= o) ? sh[t - o] : 0;
    __syncthreads();
    if (t >= o) sh[t] += y;
    __syncthreads();
  }
  int excl = sh[t] - s;
  if (base + 0 < N) rp[base + 0] = excl;
  if (base + 1 < N) rp[base + 1] = excl + c0;
  if (base + 2 < N) rp[base + 2] = excl + c0 + c1;
  if (base + 3 < N) rp[base + 3] = excl + c0 + c1 + c2;
  if (t == 255) bsum[blockIdx.x] = sh[255];
}

__global__ void k_scan2(int* __restrict__ bsum, int NB) {
  if (threadIdx.x == 0 && blockIdx.x == 0) {
    int run = 0;
    for (int i = 0; i < NB; ++i) { int x = bsum[i]; bsum[i] = run; run += x; }
  }
}

__global__ void k_scan3(int* __restrict__ rp, int* __restrict__ nxt,
                        const int* __restrict__ bsum, int N, int twoE) {
  int i = blockIdx.x * 256 + threadIdx.x;
  if (i < N) {
    int val = rp[i] + bsum[i >> 10];
    rp[i] = val;
    nxt[i] = val;
  } else if (i == N) {
    rp[N] = twoE;
  }
}

// ---- scatter edge records: rec[pos] = (src_bits, cr, ci, 0) -----------------
__global__ void k_scatter(const int* __restrict__ u, const int* __restrict__ v,
                          const float* __restrict__ w, const float* __restrict__ deg,
                          int* __restrict__ nxt, float4* __restrict__ rec, int E) {
  int e = blockIdx.x * 256 + threadIdx.x;
  if (e >= E) return;
  int a = u[e], b = v[e];
  float we = w[e];
  float da = deg[a], db = deg[b];
  float ia = da > 0.f ? rsqrtf(da) : 0.f;
  float ib = db > 0.f ? rsqrtf(db) : 0.f;
  float norm = ia * (0.5f * we) * ib;
  float th = 1.57079632679489662f * we;  // 2*pi*q*w, q=0.25
  float sn, cs;
  sincosf(th, &sn, &cs);
  float cr = -norm * cs, ci = -norm * sn;
  int p1 = atomicAdd(&nxt[b], 1);  // forward a->b, coeff (cr, ci)
  rec[p1] = make_float4(__int_as_float(a), cr, ci, 0.f);
  int p2 = atomicAdd(&nxt[a], 1);  // reverse b->a, coeff (cr, -ci)
  rec[p2] = make_float4(__int_as_float(b), cr, -ci, 0.f);
}

// ---- pack weights: Wp[k*192 + {0:64,64:128,128:192}] = {W1, W2, W0-W2} ------
__global__ void k_pack(const float* __restrict__ W, float* __restrict__ Wp, int K) {
  int i = blockIdx.x * 256 + threadIdx.x;
  if (i >= K * 64) return;
  int k = i >> 6, c = i & 63;
  float w0 = W[i], w1 = W[K * 64 + i], w2 = W[2 * K * 64 + i];
  Wp[k * 192 + c] = w1;
  Wp[k * 192 + 64 + c] = w2;
  Wp[k * 192 + 128 + c] = w0 - w2;
}

// ---- tiled f32 GEMM: C[M x 192] (64-col block per blockIdx.y) ---------------
template <int K>
__global__ __launch_bounds__(256) void k_gemm(const float* __restrict__ A,
                                              const float* __restrict__ Wp,
                                              float* __restrict__ C, int M) {
  __shared__ float As[64][68];
  __shared__ float Ws[64][64];
  const int t = threadIdx.x;
  const int r0 = blockIdx.x * 64;
  const int cb = blockIdx.y * 64;
  const int tc = t & 15, tr = t >> 4;
  float acc[4][4] = {};
  for (int k0 = 0; k0 < K; k0 += 64) {
    for (int li = t; li < 64 * 16; li += 256) {
      int row = li >> 4, c4 = li & 15;
      int gr = r0 + row;
      float4 a4 = (gr < M) ? ld4(&A[(size_t)gr * K + k0 + c4 * 4])
                           : make_float4(0.f, 0.f, 0.f, 0.f);
      *reinterpret_cast<float4*>(&As[row][c4 * 4]) = a4;
    }
    for (int li = t; li < 64 * 16; li += 256) {
      int row = li >> 4, c4 = li & 15;
      *reinterpret_cast<float4*>(&Ws[row][c4 * 4]) =
          ld4(&Wp[(size_t)(k0 + row) * 192 + cb + c4 * 4]);
    }
    __syncthreads();
    for (int k = 0; k < 64; ++k) {
      float4 b4 = *reinterpret_cast<const float4*>(&Ws[k][tc * 4]);
      float a0 = As[tr * 4 + 0][k], a1 = As[tr * 4 + 1][k];
      float a2 = As[tr * 4 + 2][k], a3 = As[tr * 4 + 3][k];
      acc[0][0] += a0 * b4.x; acc[0][1] += a0 * b4.y; acc[0][2] += a0 * b4.z; acc[0][3] += a0 * b4.w;
      acc[1][0] += a1 * b4.x; acc[1][1] += a1 * b4.y; acc[1][2] += a1 * b4.z; acc[1][3] += a1 * b4.w;
      acc[2][0] += a2 * b4.x; acc[2][1] += a2 * b4.y; acc[2][2] += a2 * b4.z; acc[2][3] += a2 * b4.w;
      acc[3][0] += a3 * b4.x; acc[3][1] += a3 * b4.y; acc[3][2] += a3 * b4.z; acc[3][3] += a3 * b4.w;
    }
    __syncthreads();
  }
#pragma unroll
  for (int i = 0; i < 4; ++i) {
    int gr = r0 + tr * 4 + i;
    if (gr < M)
      *reinterpret_cast<float4*>(&C[(size_t)gr * 192 + cb + tc * 4]) =
          make_float4(acc[i][0], acc[i][1], acc[i][2], acc[i][3]);
  }
}

// ---- gather A: hr/hi = base + T1, U0..U3 = prop of G2 -----------------------
__global__ __launch_bounds__(256) void k_gatherA(
    const float4* __restrict__ rec, const int* __restrict__ rp,
    const float* __restrict__ Cr, const float* __restrict__ Ci,
    const float* __restrict__ b,
    float* __restrict__ Hr, float* __restrict__ Hi,
    float* __restrict__ U0, float* __restrict__ U1,
    float* __restrict__ U2, float* __restrict__ U3, int N) {
  int d = blockIdx.x * 4 + (threadIdx.x >> 6);
  if (d >= N) return;
  int lane = threadIdx.x & 63;
  size_t rowc = (size_t)d * 192;
  float mr = Cr[rowc + 128 + lane], mi = Ci[rowc + 128 + lane];
  float bb = b[lane];
  float hr = mr - mi + bb, hi = mr + mi + bb;
  float u0 = 0.f, u1 = 0.f, u2 = 0.f, u3 = 0.f;
  int k1 = rp[d + 1];
#pragma unroll 2
  for (int k = rp[d]; k < k1; ++k) {
    float4 r = rec[k];
    int s = __float_as_int(r.x);
    float cr = r.y, ci = r.z;
    size_t rs = (size_t)s * 192;
    float g1r = Cr[rs + lane], g1i = Ci[rs + lane];
    float g2r = Cr[rs + 64 + lane], g2i = Ci[rs + 64 + lane];
    hr += cr * g1r - ci * g1i;
    hi += ci * g1r + cr * g1i;
    u0 += cr * g2r; u1 += ci * g2i; u2 += ci * g2r; u3 += cr * g2i;
  }
  size_t o = (size_t)d * 64 + lane;
  Hr[o] = hr; Hi[o] = hi;
  U0[o] = u0; U1[o] = u1; U2[o] = u2; U3[o] = u3;
}

// ---- gather B: hr/hi += 2*prop(U), then complex relu, stores final x --------
__global__ __launch_bounds__(256) void k_gatherB(
    const float4* __restrict__ rec, const int* __restrict__ rp,
    const float* __restrict__ U0, const float* __restrict__ U1,
    const float* __restrict__ U2, const float* __restrict__ U3,
    float* __restrict__ Hr, float* __restrict__ Hi, int N) {
  int d = blockIdx.x * 4 + (threadIdx.x >> 6);
  if (d >= N) return;
  int lane = threadIdx.x & 63;
  size_t o = (size_t)d * 64 + lane;
  float hr = Hr[o], hi = Hi[o];
  int k1 = rp[d + 1];
#pragma unroll 2
  for (int k = rp[d]; k < k1; ++k) {
    float4 r = rec[k];
    int s = __float_as_int(r.x);
    float cr = 2.f * r.y, ci = 2.f * r.z;
    size_t rs = (size_t)s * 64 + lane;
    hr += cr * U0[rs] - ci * U1[rs];
    hi += ci * U2[rs] + cr * U3[rs];
  }
  if (hr < 0.f) { hr = 0.f; hi = 0.f; }  // complex relu (mask = real >= 0)
  Hr[o] = hr;
  Hi[o] = hi;
}

// ---- query gather + linear + log_softmax ------------------------------------
__global__ __launch_bounds__(256) void k_query(
    const int* __restrict__ qe, const float* __restrict__ xr,
    const float* __restrict__ xi, const float* __restrict__ Wlin,
    const float* __restrict__ blin, float* __restrict__ out, int Q) {
  int q = blockIdx.x * 4 + (threadIdx.x >> 6);
  if (q >= Q) return;
  int lane = threadIdx.x & 63;
  int q0 = qe[2 * q], q1 = qe[2 * q + 1];
  float x0 = xr[(size_t)q0 * 64 + lane];
  float x1 = xr[(size_t)q1 * 64 + lane];
  float x2 = xi[(size_t)q0 * 64 + lane];
  float x3 = xi[(size_t)q1 * 64 + lane];
  float l0 = x0 * Wlin[lane] + x1 * Wlin[64 + lane] + x2 * Wlin[128 + lane] + x3 * Wlin[192 + lane];
  float l1 = x0 * Wlin[256 + lane] + x1 * Wlin[320 + lane] + x2 * Wlin[384 + lane] + x3 * Wlin[448 + lane];
#pragma unroll
  for (int o = 32; o > 0; o >>= 1) {
    l0 += __shfl_xor(l0, o);
    l1 += __shfl_xor(l1, o);
  }
  if (lane == 0) {
    l0 += blin[0];
    l1 += blin[1];
    float m = fmaxf(l0, l1);
    float lse = m + logf(expf(l0 - m) + expf(l1 - m));
    out[2 * q + 0] = l0 - lse;
    out[2 * q + 1] = l1 - lse;
  }
}

extern "C" void kernel_launch(void* const* d_in, const int* in_sizes, int n_in,
                              void* d_out, int out_size, void* d_ws, size_t ws_size,
                              hipStream_t stream) {
  const float* real = (const float*)d_in[0];
  const float* imag = (const float*)d_in[1];
  const int* ei     = (const int*)d_in[2];
  const int* qe     = (const int*)d_in[3];
  const float* ew   = (const float*)d_in[4];
  const float* W1   = (const float*)d_in[5];
  const float* b1   = (const float*)d_in[6];
  const float* W2   = (const float*)d_in[7];
  const float* b2   = (const float*)d_in[8];
  const float* Wlin = (const float*)d_in[9];
  const float* blin = (const float*)d_in[10];

  const int N = in_sizes[0] / 128;
  const int E = in_sizes[4];
  const int Q = in_sizes[3] / 2;
  const int* u = ei;
  const int* v = ei + E;

  float* ws = (float*)d_ws;
  size_t off = 0;
  auto alloc = [&](size_t n) { float* p = ws + off; off += n; return p; };
  const size_t N64 = (size_t)N * 64;
  const size_t N192 = (size_t)N * 192;

  float4* rec = (float4*)alloc((size_t)2 * E * 4);  // first: keeps 16B alignment
  float* Cr  = alloc(N192);
  float* Ci  = alloc(N192);
  float* Hr  = alloc(N64);
  float* Hi  = alloc(N64);
  float* U0  = alloc(N64);
  float* U1  = alloc(N64);
  float* U2  = alloc(N64);
  float* U3  = alloc(N64);
  float* deg = alloc(N);
  float* Wp1 = alloc(128 * 192);
  float* Wp2 = alloc(64 * 192);
  int* cnt  = (int*)alloc(N);
  int* rp   = (int*)alloc(N + 1);
  int* nxt  = (int*)alloc(N);
  int* bsum = (int*)alloc(64);
  (void)ws_size; (void)n_in; (void)out_size;

  const int eb = (E + 255) / 256;
  const int mb = (N + 63) / 64;
  const int NB = (N + 1023) / 1024;
  const int gb = (N + 3) / 4;

  // --- graph structure + coefficients ---
  hipMemsetAsync(deg, 0, (size_t)N * sizeof(float), stream);
  hipMemsetAsync(cnt, 0, (size_t)N * sizeof(int), stream);
  k_deg_count<<<eb, 256, 0, stream>>>(u, v, ew, deg, cnt, E);
  k_scan1<<<NB, 256, 0, stream>>>(cnt, rp, bsum, N);
  k_scan2<<<1, 64, 0, stream>>>(bsum, NB);
  k_scan3<<<(N + 256) / 256, 256, 0, stream>>>(rp, nxt, bsum, N, 2 * E);
  k_scatter<<<eb, 256, 0, stream>>>(u, v, ew, deg, nxt, rec, E);
  k_pack<<<(128 * 64 + 255) / 256, 256, 0, stream>>>(W1, Wp1, 128);
  k_pack<<<(64 * 64 + 255) / 256, 256, 0, stream>>>(W2, Wp2, 64);

  // --- layer 1 (F=128) ---
  k_gemm<128><<<dim3(mb, 3), 256, 0, stream>>>(real, Wp1, Cr, N);
  k_gemm<128><<<dim3(mb, 3), 256, 0, stream>>>(imag, Wp1, Ci, N);
  k_gatherA<<<gb, 256, 0, stream>>>(rec, rp, Cr, Ci, b1, Hr, Hi, U0, U1, U2, U3, N);
  k_gatherB<<<gb, 256, 0, stream>>>(rec, rp, U0, U1, U2, U3, Hr, Hi, N);

  // --- layer 2 (F=64) ---
  k_gemm<64><<<dim3(mb, 3), 256, 0, stream>>>(Hr, Wp2, Cr, N);
  k_gemm<64><<<dim3(mb, 3), 256, 0, stream>>>(Hi, Wp2, Ci, N);
  k_gatherA<<<gb, 256, 0, stream>>>(rec, rp, Cr, Ci, b2, Hr, Hi, U0, U1, U2, U3, N);
  k_gatherB<<<gb, 256, 0, stream>>>(rec, rp, U0, U1, U2, U3, Hr, Hi, N);

  // --- queries ---
  k_query<<<(Q + 3) / 4, 256, 0, stream>>>(qe, Hr, Hi, Wlin, blin, (float*)d_out, Q);
}